// Round 3
// baseline (7105.947 us; speedup 1.0000x reference)
//
#include <hip/hip_runtime.h>

// LSTM  B=64, T=2048, I=H=512, fp32 in/out.
// Phase A: convert x to bf16; pack W_i (4 gates) transposed+bf16; bias.
// Fused persistent kernel, grid = 256 wgs x 512 thr, 84KB dynamic LDS per wg
//   -> hardware can only place ONE wg per CU (2x84KB > 160KB LDS pool):
//   blockIdx 0..63  = persistent recurrence wgs (4 batch-groups x 16 col-wgs,
//                     W_h slice pinned in VGPRs, tag-embedded h exchange).
//   blockIdx 64..255 = persistent GEMM wgs looping over 16384 Gx tiles
//                     (x_t @ W_i + b) t128-major, gated to the recurrence via
//                     per-t128 release/acquire ready counters. The GEMM runs
//                     in the recurrence's shadow on 192 dedicated CUs.

typedef __attribute__((ext_vector_type(8))) short bf16x8;
typedef __attribute__((ext_vector_type(4))) float f32x4;

#define T_STEPS 2048

__device__ __forceinline__ unsigned short f2bf(float f) {
  union { float f; unsigned u; } v; v.f = f;
  unsigned r = v.u + 0x7fffu + ((v.u >> 16) & 1u);   // RNE
  return (unsigned short)(r >> 16);
}
__device__ __forceinline__ float bf2f(unsigned short b) {
  union { unsigned u; float f; } v; v.u = ((unsigned)b) << 16;
  return v.f;
}
__device__ __forceinline__ float sigm(float x)  { return 1.f / (1.f + __expf(-x)); }
__device__ __forceinline__ float tanhx(float x) { return 2.f / (1.f + __expf(-2.f * x)) - 1.f; }

// ---------------- Phase A: x fp32 -> bf16 ----------------
__global__ __launch_bounds__(256) void k_cvt(const float* __restrict__ x,
                                             unsigned short* __restrict__ xb, int n4) {
  int stride = gridDim.x * blockDim.x;
  for (int i = blockIdx.x * blockDim.x + threadIdx.x; i < n4; i += stride) {
    float4 v = ((const float4*)x)[i];
    ushort4 o;
    o.x = f2bf(v.x); o.y = f2bf(v.y); o.z = f2bf(v.z); o.w = f2bf(v.w);
    ((ushort4*)xb)[i] = o;
  }
}

// ---------------- Phase A: W_i -> Wt[p][k] bf16 (p = j*64 + g*16 + hl), bias ----------------
__global__ __launch_bounds__(128) void k_prep_w(
    const float* __restrict__ wi, const float* __restrict__ wf,
    const float* __restrict__ wg, const float* __restrict__ wo,
    const float* __restrict__ bii, const float* __restrict__ bif,
    const float* __restrict__ big, const float* __restrict__ bio,
    const float* __restrict__ bhi, const float* __restrict__ bhf,
    const float* __restrict__ bhg, const float* __restrict__ bho,
    unsigned short* __restrict__ Wt, float* __restrict__ biasp) {
  int p = blockIdx.x;
  int g = (p >> 4) & 3, jj = p >> 6, hl = p & 15;
  int hcol = jj * 16 + hl;
  const float* w = (g == 0) ? wi : (g == 1) ? wf : (g == 2) ? wg : wo;
  for (int k = threadIdx.x; k < 512; k += 128)
    Wt[(long)p * 512 + k] = f2bf(w[(long)k * 512 + hcol]);
  if (threadIdx.x == 0) {
    const float* bi = (g == 0) ? bii : (g == 1) ? bif : (g == 2) ? big : bio;
    const float* bh = (g == 0) ? bhi : (g == 1) ? bhf : (g == 2) ? bhg : bho;
    biasp[p] = bi[hcol] + bh[hcol];
  }
}

// ---------------- Fused: persistent recurrence + shadow GEMM (1 wg/CU) ----------------
__global__ __launch_bounds__(512, 1) void k_fused(
    const float* __restrict__ Whi, const float* __restrict__ Whf,
    const float* __restrict__ Whg, const float* __restrict__ Who,
    unsigned short* __restrict__ Gx,         // [T][32][4][16][64] bf16
    unsigned long long* __restrict__ hbuf,   // [2][64][256] u64, zeroed
    unsigned int* __restrict__ tcnt,         // [16], zeroed
    float* __restrict__ out,
    const unsigned short* __restrict__ A,    // xb [131072][512] bf16
    const unsigned short* __restrict__ Bt,   // Wt [2048][512] bf16
    const float* __restrict__ biasp) {       // [2048]
  extern __shared__ unsigned char smem[];    // 86016 B requested: forces 1 wg/CU
  const int tid  = threadIdx.x;
  const int lane = tid & 63;
  const int wave = tid >> 6;
  const int quad = lane >> 4;

  if (blockIdx.x >= 64) {
    // ================= GEMM role: persistent, 192 wgs =================
    unsigned short* lA = (unsigned short*)smem;          // [128][64] swizzled
    unsigned short* lB = lA + 8192;                      // [128][64] swizzled
    unsigned short* lC = (unsigned short*)smem;          // epilogue reuse [128][128]
    const int gw   = blockIdx.x - 64;                    // 0..191
    const int wm   = (wave >> 2) * 64;
    const int wn   = (wave & 3) * 32;
    const int lrow = lane & 15;

    for (int tileid = gw; tileid < 16384; tileid += 192) {
      const int t128 = tileid >> 10;
      const int rem  = tileid & 1023;
      const long m0  = (long)(rem >> 4) * 2048 + t128 * 128;
      const int p0   = (rem & 15) * 128;

      f32x4 acc[4][2] = {};

      for (int kb = 0; kb < 512; kb += 64) {
        __syncthreads();
#pragma unroll
        for (int it = 0; it < 2; ++it) {      // stage 128 rows x 64 k, XOR-swizzled
          int ci = it * 512 + tid;
          int row = ci >> 3, c8 = ci & 7;
          int c8p = c8 ^ (row & 7);
          *(int4*)&lA[row * 64 + c8p * 8] = *(const int4*)(A + (m0 + row) * 512 + kb + c8 * 8);
          *(int4*)&lB[row * 64 + c8p * 8] = *(const int4*)(Bt + (long)(p0 + row) * 512 + kb + c8 * 8);
        }
        __syncthreads();
#pragma unroll
        for (int kk = 0; kk < 2; ++kk) {
          int c8 = kk * 4 + quad;
          bf16x8 af[4], bfr[2];
#pragma unroll
          for (int i = 0; i < 4; ++i) {
            int m = wm + i * 16 + lrow;
            af[i]  = *(const bf16x8*)&lA[m * 64 + ((c8 ^ (m & 7)) * 8)];
          }
#pragma unroll
          for (int n = 0; n < 2; ++n) {
            int p = wn + n * 16 + lrow;
            bfr[n] = *(const bf16x8*)&lB[p * 64 + ((c8 ^ (p & 7)) * 8)];
          }
#pragma unroll
          for (int i = 0; i < 4; ++i)
#pragma unroll
            for (int n = 0; n < 2; ++n)
              acc[i][n] = __builtin_amdgcn_mfma_f32_16x16x32_bf16(af[i], bfr[n], acc[i][n], 0, 0, 0);
        }
      }

      float bl[2];
#pragma unroll
      for (int n = 0; n < 2; ++n) bl[n] = biasp[p0 + wn + n * 16 + lrow];

      __syncthreads();
#pragma unroll
      for (int i = 0; i < 4; ++i)
#pragma unroll
        for (int n = 0; n < 2; ++n) {
          int col = wn + n * 16 + lrow;
#pragma unroll
          for (int r4 = 0; r4 < 4; ++r4) {
            int row = wm + i * 16 + quad * 4 + r4;      // C/D: col=lane&15, row=quad*4+reg
            lC[row * 128 + col] = f2bf(acc[i][n][r4] + bl[n]);
          }
        }
      __syncthreads();
      {
        int row = tid >> 2, seg = tid & 3;              // 4 threads/row, 32 cols each
        long m = m0 + row;
        int b = (int)(m >> 11), t = (int)(m & 2047);
        int bg = b >> 4, r = b & 15;
        int jj = (p0 >> 6) + (seg >> 1);
        unsigned short* dst = Gx + ((((long)t * 32 + jj) * 4 + bg) * 16 + r) * 64 + (seg & 1) * 32;
        const unsigned short* src = lC + row * 128 + seg * 32;
#pragma unroll
        for (int c = 0; c < 4; ++c)
          *(int4*)(dst + c * 8) = *(const int4*)(src + c * 8);
      }
      asm volatile("s_waitcnt vmcnt(0)" ::: "memory");  // own stores accepted by L2
      __syncthreads();                                  // all threads' stores accepted
      if (tid == 0)                                     // RELEASE@agent: L2 writeback + publish
        __hip_atomic_fetch_add(&tcnt[t128], 1u, __ATOMIC_RELEASE, __HIP_MEMORY_SCOPE_AGENT);
    }
    return;
  }

  // ================= LSTM role: 64 wgs, 1/CU =================
  float (*gl)[2][16][33] = (float (*)[2][16][33])smem;        // 16896 B
  unsigned char* hlds = smem + 17408;                         // 16 KB, 16x512 bf16 swizzled

  const int wg   = blockIdx.x;        // 0..63
  const int bg   = wg >> 4;           // 0..3  (batch rows bg*16..+15)
  const int slot = wg & 15;           // 0..15 (h cols slot*32..+31)
  const int gate = wave & 3;
  const int kh   = wave >> 2;         // K-half 0..1
  const int hl   = lane & 15;
  const int j0   = slot * 32;

  const float* Wh = (gate == 0) ? Whi : (gate == 1) ? Whf : (gate == 2) ? Whg : Who;
  union WFrag { bf16x8 v; unsigned u[4]; };
  WFrag wfrag[2][8];                  // [colset][kk]: B[k][n], k = kh*256 + kk*32 + quad*8 + i
#pragma unroll
  for (int cs = 0; cs < 2; ++cs) {
    const int hcol = j0 + cs * 16 + hl;
#pragma unroll
    for (int kk = 0; kk < 8; ++kk) {
      int kbase = kh * 256 + kk * 32 + quad * 8;
      bf16x8 t;
#pragma unroll
      for (int i = 0; i < 8; ++i)
        t[i] = (short)f2bf(Wh[(long)(kbase + i) * 512 + hcol]);
      wfrag[cs][kk].v = t;
    }
  }
#pragma unroll
  for (int cs = 0; cs < 2; ++cs)
#pragma unroll
    for (int kk = 0; kk < 8; ++kk)
#pragma unroll
      for (int r = 0; r < 4; ++r)
        asm volatile("" : "+v"(wfrag[cs][kk].u[r]));    // pin weights in VGPRs

  unsigned long long* hb0 = hbuf;
  unsigned long long* hb1 = hbuf + 64 * 256;

  const int er  = tid >> 5;           // 0..15 epilogue row
  const int ec  = tid & 31;           // 0..31 epilogue col
  const int r_a = lane & 15;          // MFMA A row

  float c_val = 0.f;
  float h_val = 0.f;

  for (int s = 0; s < T_STEPS; ++s) {
    if ((s & 127) == 0) {             // Gx block readiness (amortized, ACQUIRE->buffer_inv)
      if (tid == 0) {
        while (__hip_atomic_load(&tcnt[s >> 7], __ATOMIC_ACQUIRE,
                                 __HIP_MEMORY_SCOPE_AGENT) < 1024u)
          __builtin_amdgcn_s_sleep(8);
      }
      __syncthreads();
    }

    // x-gate contributions: independent of h, issue before the tag-wait.
    const unsigned short* gxp =
        Gx + ((((long)s * 32 + (j0 >> 4) + (ec >> 4)) * 4 + bg) * 16 + er) * 64 + (ec & 15);
    unsigned short gxi = gxp[0], gxf = gxp[16], gxg = gxp[32], gxo = gxp[48];

    const unsigned long long* hcur = (s & 1) ? hb1 : hb0;
    unsigned long long* hnxt       = (s & 1) ? hb0 : hb1;
    const unsigned long long* hbase = hcur + bg * 4096;   // this bg's 16x256 words
    const unsigned exp_tag = (unsigned)s;                 // h_{s-1} carries tag s

    // Cooperative tagged load of the 16x512 h panel: 8 u64/thread, retry stale.
    unsigned long long w[8];
#pragma unroll
    for (int c = 0; c < 8; ++c)
      w[c] = __hip_atomic_load(hbase + c * 512 + tid, __ATOMIC_RELAXED,
                               __HIP_MEMORY_SCOPE_AGENT);
    for (;;) {
      unsigned miss = 0;
#pragma unroll
      for (int c = 0; c < 8; ++c)
        miss |= ((((unsigned)(w[c] >> 32)) != exp_tag) ? 1u : 0u) << c;
      if (!__any((int)(miss != 0))) break;
#pragma unroll
      for (int c = 0; c < 8; ++c)
        if (miss & (1u << c))
          w[c] = __hip_atomic_load(hbase + c * 512 + tid, __ATOMIC_RELAXED,
                                   __HIP_MEMORY_SCOPE_AGENT);
    }

    // Strip tags -> swizzled LDS tile (row stride 1024B, byte ^= (row&7)<<4).
#pragma unroll
    for (int c = 0; c < 8; ++c) {
      int wv  = c * 512 + tid;
      int row = wv >> 8, cp = wv & 255;
      *(unsigned*)(hlds + row * 1024 + ((cp * 4) ^ ((row & 7) << 4))) = (unsigned)w[c];
    }
    __syncthreads();                                      // #1: hlds staged

    // MFMA: 4 independent chains of 4 (latency hiding); af feeds both colsets.
    f32x4 a0e = {0.f,0.f,0.f,0.f}, a0o = {0.f,0.f,0.f,0.f};
    f32x4 a1e = {0.f,0.f,0.f,0.f}, a1o = {0.f,0.f,0.f,0.f};
#pragma unroll
    for (int kk = 0; kk < 8; kk += 2) {
      int b0 = kh * 512 + kk * 64 + quad * 16;
      bf16x8 afe = *(const bf16x8*)(hlds + r_a * 1024 + (b0 ^ ((r_a & 7) << 4)));
      bf16x8 afo = *(const bf16x8*)(hlds + r_a * 1024 + ((b0 + 64) ^ ((r_a & 7) << 4)));
      a0e = __builtin_amdgcn_mfma_f32_16x16x32_bf16(afe, wfrag[0][kk].v,     a0e, 0, 0, 0);
      a1e = __builtin_amdgcn_mfma_f32_16x16x32_bf16(afe, wfrag[1][kk].v,     a1e, 0, 0, 0);
      a0o = __builtin_amdgcn_mfma_f32_16x16x32_bf16(afo, wfrag[0][kk + 1].v, a0o, 0, 0, 0);
      a1o = __builtin_amdgcn_mfma_f32_16x16x32_bf16(afo, wfrag[1][kk + 1].v, a1o, 0, 0, 0);
    }
    f32x4 acc0 = a0e + a0o, acc1 = a1e + a1o;
#pragma unroll
    for (int i = 0; i < 4; ++i) {
      gl[gate][kh][quad * 4 + i][hl]      = acc0[i];      // C/D: col=lane&15, row=quad*4+reg
      gl[gate][kh][quad * 4 + i][16 + hl] = acc1[i];
    }
    __syncthreads();                                      // #2: gl ready (also fences hlds reads)

    float ui = gl[0][0][er][ec] + gl[0][1][er][ec] + bf2f(gxi);
    float uf = gl[1][0][er][ec] + gl[1][1][er][ec] + bf2f(gxf);
    float ug = gl[2][0][er][ec] + gl[2][1][er][ec] + bf2f(gxg);
    float uo = gl[3][0][er][ec] + gl[3][1][er][ec] + bf2f(gxo);
    float ig = sigm(ui), fg = sigm(uf), gg = tanhx(ug), og = sigm(uo);
    c_val = fg * c_val + ig * gg;
    h_val = og * tanhx(c_val);

    // Publish: 2 bf16 + tag per u64, fire-and-forget.
    unsigned hv = (unsigned)f2bf(h_val);
    unsigned other = (unsigned)__shfl_xor((int)hv, 1, 64);
    if (!(tid & 1)) {
      unsigned pack = (hv & 0xffffu) | (other << 16);
      unsigned long long word =
          (((unsigned long long)(unsigned)(s + 1)) << 32) | (unsigned long long)pack;
      int cp = (j0 + ec) >> 1;
      __hip_atomic_store(hnxt + (bg * 16 + er) * 256 + cp, word,
                         __ATOMIC_RELAXED, __HIP_MEMORY_SCOPE_AGENT);
    }
    // No loop-end barrier: hlds(s+1) writes are after #2(s) for every wave
    // (all af-reads done), and gl(s+1) writes are after #1(s+1) which waits
    // for every thread's gl(s) epilogue reads.
  }

  int b = bg * 16 + er;
  out[(long)b * 512 + j0 + ec]         = h_val;   // h_T
  out[32768 + (long)b * 512 + j0 + ec] = c_val;   // c_T
}

// ---------------- launcher ----------------
extern "C" void kernel_launch(void* const* d_in, const int* in_sizes, int n_in,
                              void* d_out, int out_size, void* d_ws, size_t ws_size,
                              hipStream_t stream) {
  const float* x    = (const float*)d_in[0];
  const float* w_ii = (const float*)d_in[1];
  const float* w_hi = (const float*)d_in[2];
  const float* b_ii = (const float*)d_in[3];
  const float* b_hi = (const float*)d_in[4];
  const float* w_if = (const float*)d_in[5];
  const float* w_hf = (const float*)d_in[6];
  const float* b_if_= (const float*)d_in[7];
  const float* b_hf = (const float*)d_in[8];
  const float* w_ig = (const float*)d_in[9];
  const float* w_hg = (const float*)d_in[10];
  const float* b_ig = (const float*)d_in[11];
  const float* b_hg = (const float*)d_in[12];
  const float* w_io = (const float*)d_in[13];
  const float* w_ho = (const float*)d_in[14];
  const float* b_io = (const float*)d_in[15];
  const float* b_ho = (const float*)d_in[16];

  char* ws = (char*)d_ws;
  // layout: Gx 512MB | xb 128MB | Wt 2MB | biasp 8KB | hbuf 256KB | tcnt 64B
  unsigned short* Gx   = (unsigned short*)(ws);
  unsigned short* xb   = (unsigned short*)(ws + 536870912L);
  unsigned short* Wt   = (unsigned short*)(ws + 671088640L);
  float* biasp         = (float*)(ws + 673185792L);
  unsigned long long* hbuf = (unsigned long long*)(ws + 673193984L);
  unsigned int* tcnt   = (unsigned int*)(ws + 673193984L + 2L * 64 * 256 * 8);

  static int attr_set = 0;
  if (!attr_set) {
    hipFuncSetAttribute(reinterpret_cast<const void*>(k_fused),
                        hipFuncAttributeMaxDynamicSharedMemorySize, 86016);
    attr_set = 1;
  }

  hipMemsetAsync(hbuf, 0, 2L * 64 * 256 * 8 + 64, stream);  // h tags + tcnt

  k_cvt<<<8192, 256, 0, stream>>>(x, xb, (64 * 2048 * 512) / 4);
  k_prep_w<<<2048, 128, 0, stream>>>(w_ii, w_if, w_ig, w_io,
                                     b_ii, b_if_, b_ig, b_io,
                                     b_hi, b_hf, b_hg, b_ho,
                                     Wt, biasp);
  k_fused<<<256, 512, 86016, stream>>>(w_hi, w_hf, w_hg, w_ho,
                                       Gx, hbuf, tcnt, (float*)d_out,
                                       xb, Wt, biasp);
}

// Round 4
// 6555.133 us; speedup vs baseline: 1.0840x; 1.0840x over previous
//
#include <hip/hip_runtime.h>

// LSTM  B=64, T=2048, I=H=512, fp32 in/out.
// Phase A: convert x to bf16; pack W_i (4 gates) transposed+bf16; bias.
// Fused persistent kernel, grid = 256 wgs x 512 thr, 84KB dynamic LDS per wg
//   -> hardware can only place ONE wg per CU (2x84KB > 160KB LDS pool):
//   blockIdx 0..63  = persistent recurrence wgs, EXACT round-1 body
//                     (tag-embedded h exchange, loop-end barrier, 2-acc MFMA).
//   blockIdx 64..255 = persistent GEMM wgs looping over 16384 Gx tiles,
//                     THROTTLED to stay ~2 blocks ahead of the recurrence
//                     (paced by sprog), publishing per-t128 ready counts.

typedef __attribute__((ext_vector_type(8))) short bf16x8;
typedef __attribute__((ext_vector_type(4))) float f32x4;

#define T_STEPS 2048

__device__ __forceinline__ unsigned short f2bf(float f) {
  union { float f; unsigned u; } v; v.f = f;
  unsigned r = v.u + 0x7fffu + ((v.u >> 16) & 1u);   // RNE
  return (unsigned short)(r >> 16);
}
__device__ __forceinline__ float bf2f(unsigned short b) {
  union { unsigned u; float f; } v; v.u = ((unsigned)b) << 16;
  return v.f;
}
__device__ __forceinline__ float sigm(float x)  { return 1.f / (1.f + __expf(-x)); }
__device__ __forceinline__ float tanhx(float x) { return 2.f / (1.f + __expf(-2.f * x)) - 1.f; }

// ---------------- Phase A: x fp32 -> bf16 ----------------
__global__ __launch_bounds__(256) void k_cvt(const float* __restrict__ x,
                                             unsigned short* __restrict__ xb, int n4) {
  int stride = gridDim.x * blockDim.x;
  for (int i = blockIdx.x * blockDim.x + threadIdx.x; i < n4; i += stride) {
    float4 v = ((const float4*)x)[i];
    ushort4 o;
    o.x = f2bf(v.x); o.y = f2bf(v.y); o.z = f2bf(v.z); o.w = f2bf(v.w);
    ((ushort4*)xb)[i] = o;
  }
}

// ---------------- Phase A: W_i -> Wt[p][k] bf16 (p = j*64 + g*16 + hl), bias ----------------
__global__ __launch_bounds__(128) void k_prep_w(
    const float* __restrict__ wi, const float* __restrict__ wf,
    const float* __restrict__ wg, const float* __restrict__ wo,
    const float* __restrict__ bii, const float* __restrict__ bif,
    const float* __restrict__ big, const float* __restrict__ bio,
    const float* __restrict__ bhi, const float* __restrict__ bhf,
    const float* __restrict__ bhg, const float* __restrict__ bho,
    unsigned short* __restrict__ Wt, float* __restrict__ biasp) {
  int p = blockIdx.x;
  int g = (p >> 4) & 3, jj = p >> 6, hl = p & 15;
  int hcol = jj * 16 + hl;
  const float* w = (g == 0) ? wi : (g == 1) ? wf : (g == 2) ? wg : wo;
  for (int k = threadIdx.x; k < 512; k += 128)
    Wt[(long)p * 512 + k] = f2bf(w[(long)k * 512 + hcol]);
  if (threadIdx.x == 0) {
    const float* bi = (g == 0) ? bii : (g == 1) ? bif : (g == 2) ? big : bio;
    const float* bh = (g == 0) ? bhi : (g == 1) ? bhf : (g == 2) ? bhg : bho;
    biasp[p] = bi[hcol] + bh[hcol];
  }
}

// ---------------- Fused: persistent recurrence + throttled shadow GEMM ----------------
// sync[0..15] = tcnt per t128 block (release/acquire), sync[16] = sprog (LSTM step).
__global__ __launch_bounds__(512, 1) void k_fused(
    const float* __restrict__ Whi, const float* __restrict__ Whf,
    const float* __restrict__ Whg, const float* __restrict__ Who,
    unsigned short* __restrict__ Gx,         // [T][32][4][16][64] bf16
    unsigned long long* __restrict__ hbuf,   // [2][64][256] u64, zeroed
    unsigned int* __restrict__ sync,         // [17], zeroed
    float* __restrict__ out,
    const unsigned short* __restrict__ A,    // xb [131072][512] bf16
    const unsigned short* __restrict__ Bt,   // Wt [2048][512] bf16
    const float* __restrict__ biasp) {       // [2048]
  extern __shared__ unsigned char smem[];    // 86016 B requested: forces 1 wg/CU
  const int tid  = threadIdx.x;
  const int lane = tid & 63;
  const int wave = tid >> 6;
  const int quad = lane >> 4;

  if (blockIdx.x >= 64) {
    // ================= GEMM role: persistent, 192 wgs, JIT-throttled =================
    unsigned short* lA = (unsigned short*)smem;          // [128][64] swizzled
    unsigned short* lB = lA + 8192;                      // [128][64] swizzled
    unsigned short* lC = (unsigned short*)smem;          // epilogue reuse [128][128]
    const int gw   = blockIdx.x - 64;                    // 0..191
    const int wm   = (wave >> 2) * 64;
    const int wn   = (wave & 3) * 32;
    const int lrow = lane & 15;

    for (int tileid = gw; tileid < 16384; tileid += 192) {
      const int t128 = tileid >> 10;
      const int rem  = tileid & 1023;
      const long m0  = (long)(rem >> 4) * 2048 + t128 * 128;
      const int p0   = (rem & 15) * 128;

      // Pace: stay <=2 blocks ahead of the recurrence (spreads LLC pressure).
      if (tid == 0) {
        int need = (t128 - 2) * 128;
        if (need > 0)
          while ((int)__hip_atomic_load(&sync[16], __ATOMIC_RELAXED,
                                        __HIP_MEMORY_SCOPE_AGENT) < need)
            __builtin_amdgcn_s_sleep(32);
      }
      __syncthreads();

      f32x4 acc[4][2] = {};

      for (int kb = 0; kb < 512; kb += 64) {
        __syncthreads();
#pragma unroll
        for (int it = 0; it < 2; ++it) {      // stage 128 rows x 64 k, XOR-swizzled
          int ci = it * 512 + tid;
          int row = ci >> 3, c8 = ci & 7;
          int c8p = c8 ^ (row & 7);
          *(int4*)&lA[row * 64 + c8p * 8] = *(const int4*)(A + (m0 + row) * 512 + kb + c8 * 8);
          *(int4*)&lB[row * 64 + c8p * 8] = *(const int4*)(Bt + (long)(p0 + row) * 512 + kb + c8 * 8);
        }
        __syncthreads();
#pragma unroll
        for (int kk = 0; kk < 2; ++kk) {
          int c8 = kk * 4 + quad;
          bf16x8 af[4], bfr[2];
#pragma unroll
          for (int i = 0; i < 4; ++i) {
            int m = wm + i * 16 + lrow;
            af[i]  = *(const bf16x8*)&lA[m * 64 + ((c8 ^ (m & 7)) * 8)];
          }
#pragma unroll
          for (int n = 0; n < 2; ++n) {
            int p = wn + n * 16 + lrow;
            bfr[n] = *(const bf16x8*)&lB[p * 64 + ((c8 ^ (p & 7)) * 8)];
          }
#pragma unroll
          for (int i = 0; i < 4; ++i)
#pragma unroll
            for (int n = 0; n < 2; ++n)
              acc[i][n] = __builtin_amdgcn_mfma_f32_16x16x32_bf16(af[i], bfr[n], acc[i][n], 0, 0, 0);
        }
      }

      float bl[2];
#pragma unroll
      for (int n = 0; n < 2; ++n) bl[n] = biasp[p0 + wn + n * 16 + lrow];

      __syncthreads();
#pragma unroll
      for (int i = 0; i < 4; ++i)
#pragma unroll
        for (int n = 0; n < 2; ++n) {
          int col = wn + n * 16 + lrow;
#pragma unroll
          for (int r4 = 0; r4 < 4; ++r4) {
            int row = wm + i * 16 + quad * 4 + r4;      // C/D: col=lane&15, row=quad*4+reg
            lC[row * 128 + col] = f2bf(acc[i][n][r4] + bl[n]);
          }
        }
      __syncthreads();
      {
        int row = tid >> 2, seg = tid & 3;              // 4 threads/row, 32 cols each
        long m = m0 + row;
        int b = (int)(m >> 11), t = (int)(m & 2047);
        int bg = b >> 4, r = b & 15;
        int jj = (p0 >> 6) + (seg >> 1);
        unsigned short* dst = Gx + ((((long)t * 32 + jj) * 4 + bg) * 16 + r) * 64 + (seg & 1) * 32;
        const unsigned short* src = lC + row * 128 + seg * 32;
#pragma unroll
        for (int c = 0; c < 4; ++c)
          *(int4*)(dst + c * 8) = *(const int4*)(src + c * 8);
      }
      asm volatile("s_waitcnt vmcnt(0)" ::: "memory");  // own stores accepted by L2
      __syncthreads();                                  // all threads' stores accepted
      if (tid == 0)                                     // RELEASE@agent: L2 writeback + publish
        __hip_atomic_fetch_add(&sync[t128], 1u, __ATOMIC_RELEASE, __HIP_MEMORY_SCOPE_AGENT);
    }
    return;
  }

  // ================= LSTM role: 64 wgs, 1/CU, EXACT round-1 body =================
  float (*gl)[2][16][33] = (float (*)[2][16][33])smem;        // 16896 B
  unsigned char* hlds = smem + 17408;                         // 16 KB, 16x512 bf16 swizzled

  const int wg   = blockIdx.x;        // 0..63
  const int bg   = wg >> 4;           // 0..3  (batch rows bg*16..+15)
  const int slot = wg & 15;           // 0..15 (h cols slot*32..+31)
  const int gate = wave & 3;
  const int kh   = wave >> 2;         // K-half 0..1
  const int hl   = lane & 15;
  const int j0   = slot * 32;

  const float* Wh = (gate == 0) ? Whi : (gate == 1) ? Whf : (gate == 2) ? Whg : Who;
  union WFrag { bf16x8 v; unsigned u[4]; };
  WFrag wfrag[2][8];                  // [colset][kk]: B[k][n], k = kh*256 + kk*32 + quad*8 + i
#pragma unroll
  for (int cs = 0; cs < 2; ++cs) {
    const int hcol = j0 + cs * 16 + hl;
#pragma unroll
    for (int kk = 0; kk < 8; ++kk) {
      int kbase = kh * 256 + kk * 32 + quad * 8;
      bf16x8 t;
#pragma unroll
      for (int i = 0; i < 8; ++i)
        t[i] = (short)f2bf(Wh[(long)(kbase + i) * 512 + hcol]);
      wfrag[cs][kk].v = t;
    }
  }
#pragma unroll
  for (int cs = 0; cs < 2; ++cs)
#pragma unroll
    for (int kk = 0; kk < 8; ++kk)
#pragma unroll
      for (int r = 0; r < 4; ++r)
        asm volatile("" : "+v"(wfrag[cs][kk].u[r]));    // pin weights in VGPRs

  unsigned long long* hb0 = hbuf;
  unsigned long long* hb1 = hbuf + 64 * 256;

  const int er  = tid >> 5;           // 0..15 epilogue row
  const int ec  = tid & 31;           // 0..31 epilogue col
  const int r_a = lane & 15;          // MFMA A row

  float c_val = 0.f;
  float h_val = 0.f;

  for (int s = 0; s < T_STEPS; ++s) {
    if ((s & 127) == 0) {             // Gx block readiness (amortized, ACQUIRE->buffer_inv)
      if (tid == 0) {
        while (__hip_atomic_load(&sync[s >> 7], __ATOMIC_ACQUIRE,
                                 __HIP_MEMORY_SCOPE_AGENT) < 1024u)
          __builtin_amdgcn_s_sleep(8);
        if (wg == 0)                  // publish progress for GEMM pacing
          __hip_atomic_store(&sync[16], (unsigned)s, __ATOMIC_RELAXED,
                             __HIP_MEMORY_SCOPE_AGENT);
      }
      __syncthreads();
    }

    // x-gate contributions: independent of h, issue before the tag-wait.
    const unsigned short* gxp =
        Gx + ((((long)s * 32 + (j0 >> 4) + (ec >> 4)) * 4 + bg) * 16 + er) * 64 + (ec & 15);
    unsigned short gxi = gxp[0], gxf = gxp[16], gxg = gxp[32], gxo = gxp[48];

    const unsigned long long* hcur = (s & 1) ? hb1 : hb0;
    unsigned long long* hnxt       = (s & 1) ? hb0 : hb1;
    const unsigned long long* hbase = hcur + bg * 4096;   // this bg's 16x256 words
    const unsigned exp_tag = (unsigned)s;                 // h_{s-1} carries tag s

    // Cooperative tagged load of the 16x512 h panel: 8 u64/thread, retry stale.
    unsigned long long w[8];
#pragma unroll
    for (int c = 0; c < 8; ++c)
      w[c] = __hip_atomic_load(hbase + c * 512 + tid, __ATOMIC_RELAXED,
                               __HIP_MEMORY_SCOPE_AGENT);
    for (;;) {
      unsigned miss = 0;
#pragma unroll
      for (int c = 0; c < 8; ++c)
        miss |= ((((unsigned)(w[c] >> 32)) != exp_tag) ? 1u : 0u) << c;
      if (!__any((int)(miss != 0))) break;
#pragma unroll
      for (int c = 0; c < 8; ++c)
        if (miss & (1u << c))
          w[c] = __hip_atomic_load(hbase + c * 512 + tid, __ATOMIC_RELAXED,
                                   __HIP_MEMORY_SCOPE_AGENT);
    }

    // Strip tags -> swizzled LDS tile (row stride 1024B, byte ^= (row&7)<<4).
#pragma unroll
    for (int c = 0; c < 8; ++c) {
      int wv  = c * 512 + tid;
      int row = wv >> 8, cp = wv & 255;
      *(unsigned*)(hlds + row * 1024 + ((cp * 4) ^ ((row & 7) << 4))) = (unsigned)w[c];
    }
    __syncthreads();                                      // #1: hlds staged

    // MFMA: 2 accumulators, 8-deep chains (round-1 form); af feeds both colsets.
    f32x4 acc0 = {0.f, 0.f, 0.f, 0.f};
    f32x4 acc1 = {0.f, 0.f, 0.f, 0.f};
#pragma unroll
    for (int kk = 0; kk < 8; ++kk) {
      int b0 = kh * 512 + kk * 64 + quad * 16;            // byte col of 8 bf16 k-slice
      bf16x8 af = *(const bf16x8*)(hlds + r_a * 1024 + (b0 ^ ((r_a & 7) << 4)));
      acc0 = __builtin_amdgcn_mfma_f32_16x16x32_bf16(af, wfrag[0][kk].v, acc0, 0, 0, 0);
      acc1 = __builtin_amdgcn_mfma_f32_16x16x32_bf16(af, wfrag[1][kk].v, acc1, 0, 0, 0);
    }
#pragma unroll
    for (int i = 0; i < 4; ++i) {
      gl[gate][kh][quad * 4 + i][hl]      = acc0[i];      // C/D: col=lane&15, row=quad*4+reg
      gl[gate][kh][quad * 4 + i][16 + hl] = acc1[i];
    }
    __syncthreads();                                      // #2: gl ready

    float ui = gl[0][0][er][ec] + gl[0][1][er][ec] + bf2f(gxi);
    float uf = gl[1][0][er][ec] + gl[1][1][er][ec] + bf2f(gxf);
    float ug = gl[2][0][er][ec] + gl[2][1][er][ec] + bf2f(gxg);
    float uo = gl[3][0][er][ec] + gl[3][1][er][ec] + bf2f(gxo);
    float ig = sigm(ui), fg = sigm(uf), gg = tanhx(ug), og = sigm(uo);
    c_val = fg * c_val + ig * gg;
    h_val = og * tanhx(c_val);

    // Publish: 2 bf16 + tag per u64, fire-and-forget.
    unsigned hv = (unsigned)f2bf(h_val);
    unsigned other = (unsigned)__shfl_xor((int)hv, 1, 64);
    if (!(tid & 1)) {
      unsigned pack = (hv & 0xffffu) | (other << 16);
      unsigned long long word =
          (((unsigned long long)(unsigned)(s + 1)) << 32) | (unsigned long long)pack;
      int cp = (j0 + ec) >> 1;
      __hip_atomic_store(hnxt + (bg * 16 + er) * 256 + cp, word,
                         __ATOMIC_RELAXED, __HIP_MEMORY_SCOPE_AGENT);
    }
    __syncthreads();                                      // loop-end barrier (round-1 form)
  }

  int b = bg * 16 + er;
  out[(long)b * 512 + j0 + ec]         = h_val;   // h_T
  out[32768 + (long)b * 512 + j0 + ec] = c_val;   // c_T
}

// ---------------- launcher ----------------
extern "C" void kernel_launch(void* const* d_in, const int* in_sizes, int n_in,
                              void* d_out, int out_size, void* d_ws, size_t ws_size,
                              hipStream_t stream) {
  const float* x    = (const float*)d_in[0];
  const float* w_ii = (const float*)d_in[1];
  const float* w_hi = (const float*)d_in[2];
  const float* b_ii = (const float*)d_in[3];
  const float* b_hi = (const float*)d_in[4];
  const float* w_if = (const float*)d_in[5];
  const float* w_hf = (const float*)d_in[6];
  const float* b_if_= (const float*)d_in[7];
  const float* b_hf = (const float*)d_in[8];
  const float* w_ig = (const float*)d_in[9];
  const float* w_hg = (const float*)d_in[10];
  const float* b_ig = (const float*)d_in[11];
  const float* b_hg = (const float*)d_in[12];
  const float* w_io = (const float*)d_in[13];
  const float* w_ho = (const float*)d_in[14];
  const float* b_io = (const float*)d_in[15];
  const float* b_ho = (const float*)d_in[16];

  char* ws = (char*)d_ws;
  // layout: Gx 512MB | xb 128MB | Wt 2MB | biasp 8KB | hbuf 256KB | sync 68B
  unsigned short* Gx   = (unsigned short*)(ws);
  unsigned short* xb   = (unsigned short*)(ws + 536870912L);
  unsigned short* Wt   = (unsigned short*)(ws + 671088640L);
  float* biasp         = (float*)(ws + 673185792L);
  unsigned long long* hbuf = (unsigned long long*)(ws + 673193984L);
  unsigned int* sync   = (unsigned int*)(ws + 673193984L + 2L * 64 * 256 * 8);

  static int attr_set = 0;
  if (!attr_set) {
    hipFuncSetAttribute(reinterpret_cast<const void*>(k_fused),
                        hipFuncAttributeMaxDynamicSharedMemorySize, 86016);
    attr_set = 1;
  }

  hipMemsetAsync(hbuf, 0, 2L * 64 * 256 * 8 + 128, stream);  // h tags + sync

  k_cvt<<<8192, 256, 0, stream>>>(x, xb, (64 * 2048 * 512) / 4);
  k_prep_w<<<2048, 128, 0, stream>>>(w_ii, w_if, w_ig, w_io,
                                     b_ii, b_if_, b_ig, b_io,
                                     b_hi, b_hf, b_hg, b_ho,
                                     Wt, biasp);
  k_fused<<<256, 512, 86016, stream>>>(w_hi, w_hf, w_hg, w_ho,
                                       Gx, hbuf, sync, (float*)d_out,
                                       xb, Wt, biasp);
}